// Round 5
// baseline (944.130 us; speedup 1.0000x reference)
//
#include <hip/hip_runtime.h>
#include <hip/hip_fp16.h>
#include <cstdint>
#include <cstddef>

#define VCUBE 35937      // 33^3
#define LUT_CH 107811    // 3*33^3

typedef float fx4 __attribute__((ext_vector_type(4)));

// ====================== grid barrier (normal launch, all blocks co-resident) ======================
// 960 blocks, 4 blocks/CU capacity (LDS 35KB, VGPR<=128 via launch_bounds) -> guaranteed residency.
// One counter slot per barrier (zeroed by hipMemsetAsync before launch), device-scope atomics.
__device__ __forceinline__ void gridbar(unsigned* ctr, int slot) {
  __syncthreads();
  if (threadIdx.x == 0) {
    __threadfence();                      // release: make stage writes visible device-wide
    atomicAdd(&ctr[slot * 16], 1u);
    while (__hip_atomic_load(&ctr[slot * 16], __ATOMIC_RELAXED,
                             __HIP_MEMORY_SCOPE_AGENT) < gridDim.x)
      __builtin_amdgcn_s_sleep(2);
    __threadfence();                      // acquire
  }
  __syncthreads();
}

// ====================== stage bodies ======================

// conv1: fused resize(2048->256) + conv3x3s2 + lrelu + per-channel sum/sumsq emission.
__device__ __forceinline__ void conv1_body(int bid, int t,
    const float* __restrict__ imgs, const float* __restrict__ w,
    const float* __restrict__ bias, float* __restrict__ out,
    float* __restrict__ So, float* __restrict__ Qo, float* smem) {
  float* s_in = smem;          // 306
  float* s_w  = smem + 320;    // 432
  int owt = bid & 7; int oh = (bid >> 3) & 127; int b = bid >> 10;
  int ow0 = owt * 16;
  int iwbase = 2*ow0 - 1;
  int ihbase = 2*oh - 1;
  for (int i = t; i < 3*3*34; i += 256) {
    int x = i % 34; int rest = i / 34; int kh = rest % 3; int ci = rest / 3;
    int ih = ihbase + kh;
    int iw = iwbase + x;
    float v = 0.f;
    if (ih >= 0 && ih < 256 && iw >= 0 && iw < 256) {
      const float* p = imgs + (size_t)(b*3+ci) * 2048 * 2048;
      int y0 = ih*8 + 3, x0 = iw*8 + 3;     // scale-8 bilinear: frac exactly 0.5
      const float* r0 = p + (size_t)y0*2048 + x0;
      const float* r1 = r0 + 2048;
      float a = r0[0], bb = r0[1], c = r1[0], d = r1[1];
      float top = a + 0.5f*(bb - a);
      float bot = c + 0.5f*(d - c);
      v = top + 0.5f*(bot - top);
    }
    s_in[i] = v;
  }
  for (int i = t; i < 16*3*9; i += 256) s_w[i] = w[i];
  __syncthreads();
  int owl = t & 15; int co = t >> 4;
  float acc = bias[co];
  const float* wp = s_w + co*27;
#pragma unroll
  for (int ci = 0; ci < 3; ci++) {
#pragma unroll
    for (int kh = 0; kh < 3; kh++) {
      const float* rp = s_in + (ci*3 + kh)*34 + 2*owl;
      acc = fmaf(rp[0], wp[ci*9 + kh*3 + 0], acc);
      acc = fmaf(rp[1], wp[ci*9 + kh*3 + 1], acc);
      acc = fmaf(rp[2], wp[ci*9 + kh*3 + 2], acc);
    }
  }
  acc = acc >= 0.f ? acc : 0.2f*acc;
  out[(((size_t)b*16 + co)*128 + oh)*128 + ow0 + owl] = acc;
  // per-channel partial sums over the 16 ow lanes of this co
  float s = acc, s2 = acc*acc;
#pragma unroll
  for (int off = 1; off < 16; off <<= 1) {
    s  += __shfl_xor(s,  off);
    s2 += __shfl_xor(s2, off);
  }
  if (owl == 0) {
    atomicAdd(&So[b*16 + co], s);
    atomicAdd(&Qo[b*16 + co], s2);
  }
  __syncthreads();
}

// generic conv3x3 s2 pad1 + lrelu; optional on-load instance-norm of input (from Si/Qi),
// optional emission of output channel sums (So/Qo).
template<int CI, int CO, int IS, int COPB, bool WLDS, bool NORM, bool EMIT>
__device__ __forceinline__ void conv_row_body(int bid, int t,
    const float* __restrict__ in, const float* __restrict__ w,
    const float* __restrict__ bias,
    const float* __restrict__ Si, const float* __restrict__ Qi,
    const float* __restrict__ gn, const float* __restrict__ ben,
    float* __restrict__ out, float* __restrict__ So, float* __restrict__ Qo,
    float* smem) {
  constexpr int OS = IS/2;
  constexpr int PW = IS + 2;
  constexpr int NG = CO/COPB;
  constexpr int E  = CI*3*PW;
  constexpr float inv_n = 1.0f / (float)(IS*IS);
  static_assert(COPB*OS == 256, "block mismatch");
  float* s_in  = smem;
  float* s_w   = smem + E;
  float* snorm = smem + E + (WLDS ? COPB*CI*9 : 0);   // 2*CI
  int grp = bid % NG; int rest = bid / NG; int oh = rest % OS; int b = rest / OS;
  if (NORM) {
    for (int i = t; i < CI; i += 256) {
      float mean = Si[b*CI + i] * inv_n;
      float var  = Qi[b*CI + i] * inv_n - mean*mean;
      float sc   = gn[i] / sqrtf(var + 1e-5f);
      snorm[i]      = sc;
      snorm[CI + i] = ben[i] - mean*sc;
    }
    __syncthreads();
  }
  int ihb = 2*oh - 1;
  for (int i = t; i < E; i += 256) {
    int x = i % PW; int r2 = i / PW; int kh = r2 % 3; int ci = r2 / 3;
    int ih = ihb + kh; int iw = x - 1;
    float v = 0.f;
    if (ih >= 0 && ih < IS && iw >= 0 && iw < IS) {
      v = in[((size_t)(b*CI + ci)*IS + ih)*IS + iw];
      if (NORM) v = fmaf(v, snorm[ci], snorm[CI + ci]);
    }
    s_in[i] = v;
  }
  if (WLDS) {
    const float* wg = w + (size_t)grp*COPB*CI*9;
    for (int i = t; i < COPB*CI*9; i += 256) s_w[i] = wg[i];
  }
  __syncthreads();
  int ow = t % OS; int col = t / OS;
  int co = grp*COPB + col;
  float acc = bias[co];
  const float* wp = WLDS ? (s_w + col*CI*9) : (w + (size_t)co*CI*9);
  for (int ci = 0; ci < CI; ci++) {
    const float* rowp = s_in + ci*3*PW;
    const float* wc = wp + ci*9;
#pragma unroll
    for (int kh = 0; kh < 3; kh++) {
      const float* rp = rowp + kh*PW + 2*ow;
      acc = fmaf(rp[0], wc[kh*3 + 0], acc);
      acc = fmaf(rp[1], wc[kh*3 + 1], acc);
      acc = fmaf(rp[2], wc[kh*3 + 2], acc);
    }
  }
  acc = acc >= 0.f ? acc : 0.2f*acc;
  out[(((size_t)b*CO + co)*OS + oh)*OS + ow] = acc;
  if (EMIT) {
    float s = acc, s2 = acc*acc;
#pragma unroll
    for (int off = 1; off < OS; off <<= 1) {
      s  += __shfl_xor(s,  off);
      s2 += __shfl_xor(s2, off);
    }
    if ((t & (OS-1)) == 0) {
      atomicAdd(&So[b*CO + co], s);
      atomicAdd(&Qo[b*CO + co], s2);
    }
  }
  __syncthreads();
}

// H1: pool(128,8,8)->512 + gemv chunk. vb in [0, B*4): part covers 25 of the 99 outputs.
__device__ __forceinline__ void h1_body(int vb, int t,
    const float* __restrict__ x5,
    const float* __restrict__ wgen_w, const float* __restrict__ wgen_b,
    const float* __restrict__ ada_w, const float* __restrict__ ada_b,
    float* __restrict__ gw, float* __restrict__ logits_g, float* smem) {
  int b = vb >> 2, part = vb & 3;
  float* xv = smem;     // 512
  for (int o = t; o < 512; o += 256) {
    int c = o >> 2; int h2 = (o >> 1) & 1; int w2 = o & 1;
    const float* p = x5 + ((size_t)(b*128 + c))*64 + h2*32 + w2*4;
    float s = 0.f;
#pragma unroll
    for (int h = 0; h < 4; h++)
#pragma unroll
      for (int ww = 0; ww < 4; ww++) s += p[h*8 + ww];
    xv[o] = s * (1.f/16.f);
  }
  __syncthreads();
  int jbase = part * 25;
  int cnt = 99 - jbase; cnt = cnt > 25 ? 25 : cnt;
  int g = t >> 3, kk = t & 7;
  float s = 0.f;
  int j = jbase + g;
  if (g < cnt) {
    if (j < 96) {
      for (int k = kk; k < 512; k += 8) s = fmaf(xv[k], ada_w[k*96 + j], s);
    } else {
      int jj = j - 96;
      for (int k = kk; k < 512; k += 8) s = fmaf(xv[k], wgen_w[k*3 + jj], s);
    }
  }
  s += __shfl_xor(s, 1); s += __shfl_xor(s, 2); s += __shfl_xor(s, 4);
  if (g < cnt && kk == 0) {
    if (j < 96) logits_g[b*96 + j] = s + ada_b[j];
    else        gw[b*3 + (j - 96)] = s + wgen_b[j - 96];
  }
  __syncthreads();
}

// H2: softmax/cumsum -> vertices + 1024-bin hints. one virtual block per b.
__device__ __forceinline__ void h2_body(int b, int t,
    const float* __restrict__ logits_g,
    float* __restrict__ vertices, uint8_t* __restrict__ hints, float* smem) {
  float* lg  = smem;        // 96
  float* svp = smem + 96;   // 99
  for (int i = t; i < 96; i += 256) lg[i] = logits_g[b*96 + i];
  __syncthreads();
  if (t < 3) {
    const float* l = lg + t*32;
    float m = l[0];
#pragma unroll
    for (int i = 1; i < 32; i++) m = fmaxf(m, l[i]);
    float e[32]; float sum = 0.f;
#pragma unroll
    for (int i = 0; i < 32; i++) { e[i] = expf(l[i] - m); sum += e[i]; }
    float inv = 1.0f / sum;
    float* vp = vertices + b*99 + t*33;
    svp[t*33] = 0.f; vp[0] = 0.f;
    float cum = 0.f;
#pragma unroll
    for (int i = 0; i < 32; i++) { cum = fmaf(e[i], inv, cum); svp[t*33 + i + 1] = cum; vp[i + 1] = cum; }
  }
  __syncthreads();
  for (int e = t; e < 3072; e += 256) {
    int c = e >> 10; int bin = e & 1023;
    float q0 = (float)bin * (1.f/1024.f);
    const float* v = svp + c*33;
    int lo = 0, hi = 33;
    while (lo < hi) { int mid = (lo + hi) >> 1; if (v[mid] <= q0) lo = mid + 1; else hi = mid; }
    int idx = lo - 1; if (idx > 31) idx = 31;
    hints[b*3072 + e] = (uint8_t)idx;
  }
  __syncthreads();
}

// packed fp16 cell table. vb in [0, B*384)
__device__ __forceinline__ void ecell_body(int vb, int t,
    const float* __restrict__ basis_w, const float* __restrict__ gw,
    __half* __restrict__ ecell, int B) {
  int tid = vb*256 + t;
  int total = B * 32768 * 3;
  if (tid >= total) return;
  int cc = tid % 3;
  int cell = tid / 3;
  int r = cell & 31; int g = (cell >> 5) & 31; int bl = (cell >> 10) & 31; int b = cell >> 15;
  float w0 = gw[b*3 + 0], w1 = gw[b*3 + 1], w2 = gw[b*3 + 2];
  union { __half h[8]; uint4 u; } pk;
#pragma unroll
  for (int dbl = 0; dbl < 2; dbl++)
#pragma unroll
    for (int dg = 0; dg < 2; dg++)
#pragma unroll
      for (int dr = 0; dr < 2; dr++) {
        int flat = cc*VCUBE + ((bl + dbl)*33 + (g + dg))*33 + (r + dr);
        float val = w0*basis_w[flat] + w1*basis_w[LUT_CH + flat] + w2*basis_w[2*LUT_CH + flat];
        pk.h[dbl*4 + dg*2 + dr] = __float2half(val);
      }
  *(uint4*)((uint16_t*)ecell + (size_t)cell*32 + cc*8) = pk.u;
}

// ====================== pipeline kernel: 960 blocks (4/CU capacity - margin) ======================
__global__ __launch_bounds__(256, 4) void pipeline_kernel(
    const float* __restrict__ imgs,
    const float* __restrict__ w1, const float* __restrict__ b1,
    const float* __restrict__ g1, const float* __restrict__ be1,
    const float* __restrict__ w2, const float* __restrict__ b2,
    const float* __restrict__ g2, const float* __restrict__ be2,
    const float* __restrict__ w3, const float* __restrict__ b3,
    const float* __restrict__ g3, const float* __restrict__ be3,
    const float* __restrict__ w4, const float* __restrict__ b4,
    const float* __restrict__ g4, const float* __restrict__ be4,
    const float* __restrict__ w5, const float* __restrict__ b5,
    const float* __restrict__ wgen_w, const float* __restrict__ wgen_b,
    const float* __restrict__ basis_w,
    const float* __restrict__ ada_w, const float* __restrict__ ada_b,
    float* __restrict__ x1, float* __restrict__ x2, float* __restrict__ x3,
    float* __restrict__ x4, float* __restrict__ x5,
    float* __restrict__ S1, float* __restrict__ Q1,
    float* __restrict__ S2, float* __restrict__ Q2,
    float* __restrict__ S3, float* __restrict__ Q3,
    float* __restrict__ S4, float* __restrict__ Q4,
    float* __restrict__ logits_g, float* __restrict__ gw,
    float* __restrict__ vert, uint8_t* __restrict__ hints,
    __half* __restrict__ ecell, unsigned* ctr, int B) {
  __shared__ float smem[8832];    // 35.3 KB arena; max stage = conv3 (8704 floats)
  int t = threadIdx.x;
  int nb = gridDim.x;

  for (int vb = blockIdx.x; vb < B*1024; vb += nb)
    conv1_body(vb, t, imgs, w1, b1, x1, S1, Q1, smem);
  gridbar(ctr, 0);
  for (int vb = blockIdx.x; vb < B*512; vb += nb)
    conv_row_body<16, 32, 128, 4, true, true, true>(vb, t, x1, w2, b2,
        S1, Q1, g1, be1, x2, S2, Q2, smem);
  gridbar(ctr, 1);
  for (int vb = blockIdx.x; vb < B*256; vb += nb)
    conv_row_body<32, 64, 64, 8, true, true, true>(vb, t, x2, w3, b3,
        S2, Q2, g2, be2, x3, S3, Q3, smem);
  gridbar(ctr, 2);
  for (int vb = blockIdx.x; vb < B*128; vb += nb)
    conv_row_body<64, 128, 32, 16, false, true, true>(vb, t, x3, w4, b4,
        S3, Q3, g3, be3, x4, S4, Q4, smem);
  gridbar(ctr, 3);
  for (int vb = blockIdx.x; vb < B*32; vb += nb)
    conv_row_body<128, 128, 16, 32, false, true, false>(vb, t, x4, w5, b5,
        S4, Q4, g4, be4, x5, nullptr, nullptr, smem);
  gridbar(ctr, 4);
  for (int vb = blockIdx.x; vb < B*4; vb += nb)
    h1_body(vb, t, x5, wgen_w, wgen_b, ada_w, ada_b, gw, logits_g, smem);
  gridbar(ctr, 5);
  for (int vb = blockIdx.x; vb < B*385; vb += nb) {
    if (vb < B) h2_body(vb, t, logits_g, vert, hints, smem);
    else        ecell_body(vb - B, t, basis_w, gw, ecell, B);
  }
}

// ================= transform (R1-proven: 4 px/thread, batched gathers) =================
__device__ __forceinline__ float trilerp_cell(uint4 u, float fR, float fG, float fB) {
  const __half* h = (const __half*)&u;
  float f0 = __half2float(h[0]), f1 = __half2float(h[1]);
  float f2 = __half2float(h[2]), f3 = __half2float(h[3]);
  float f4 = __half2float(h[4]), f5 = __half2float(h[5]);
  float f6 = __half2float(h[6]), f7 = __half2float(h[7]);
  float l00 = fmaf(fR, f1 - f0, f0);
  float l01 = fmaf(fR, f3 - f2, f2);
  float L0  = fmaf(fG, l01 - l00, l00);
  float l10 = fmaf(fR, f5 - f4, f4);
  float l11 = fmaf(fR, f7 - f6, f6);
  float L1  = fmaf(fG, l11 - l10, l10);
  return fmaf(fB, L1 - L0, L0);
}

__global__ __launch_bounds__(256, 4) void transform_kernel(const float* __restrict__ imgs,
    const __half* __restrict__ ecell, const float* __restrict__ vert,
    const unsigned int* __restrict__ hintw,
    float* __restrict__ out, int B) {
  const size_t N = 2048u*2048u;
  __shared__ float sv[112];              // 3 x 36, indices 33..35 padded with 2.0
  __shared__ unsigned int shint_w[768];
  int b = blockIdx.x % B;                // XCD parity split for B=2
  int pblk = blockIdx.x / B;
  int t = threadIdx.x;
  if (t < 108) {
    int c = t / 36, i = t - c*36;
    sv[t] = (i < 33) ? vert[b*99 + c*33 + i] : 2.0f;
  }
  for (int i = t; i < 768; i += 256) shint_w[i] = hintw[b*768 + i];
  __syncthreads();
  const uint8_t* shint = (const uint8_t*)shint_w;
  size_t pix = ((size_t)pblk*256 + t) * 4;
  const float* ip = imgs + (size_t)b*3*N;
  float* op = out + (size_t)b*3*N;
  const __half* ec = ecell + (size_t)b*1048576;

  fx4 r  = __builtin_nontemporal_load((const fx4*)(ip + pix));
  fx4 g  = __builtin_nontemporal_load((const fx4*)(ip + N + pix));
  fx4 bb = __builtin_nontemporal_load((const fx4*)(ip + 2*N + pix));

  float qv[3][4] = { { r.x, r.y, r.z, r.w },
                     { g.x, g.y, g.z, g.w },
                     { bb.x, bb.y, bb.z, bb.w } };
  int   idxv[3][4];
  float frv[3][4];

#pragma unroll
  for (int c = 0; c < 3; c++) {
#pragma unroll
    for (int p = 0; p < 4; p++) {
      float qc = fminf(fmaxf(qv[c][p], 0.f), 1.f);
      int bin = (int)(qc * 1024.f); bin = bin > 1023 ? 1023 : bin;
      int h = shint[(c << 10) + bin];
      const float* vv = sv + c*36 + h;
      float v0 = vv[0], v1 = vv[1], v2 = vv[2], v3 = vv[3], v4 = vv[4];
      int cnt = (int)(v1 <= qc) + (int)(v2 <= qc) + (int)(v3 <= qc);
      int cmax = 31 - h; cnt = cnt < cmax ? cnt : cmax;
      float lo = v0, hi = v1;
      lo = cnt >= 1 ? v1 : lo;  hi = cnt >= 1 ? v2 : hi;
      lo = cnt >= 2 ? v2 : lo;  hi = cnt >= 2 ? v3 : hi;
      lo = cnt >= 3 ? v3 : lo;  hi = cnt >= 3 ? v4 : hi;
      idxv[c][p] = h + cnt;
      float f = (qc - lo) * __builtin_amdgcn_rcpf(fmaxf(hi - lo, 1e-10f));
      frv[c][p] = fminf(fmaxf(f, 0.f), 1.f);
    }
  }

  uint4 u0[4], u1[4], u2[4];
#pragma unroll
  for (int p = 0; p < 4; p++) {
    const __half* cell = ec +
        ((size_t)(((idxv[2][p] << 5) + idxv[1][p]) << 5) + idxv[0][p]) * 32;
    u0[p] = *(const uint4*)(cell);
    u1[p] = *(const uint4*)(cell + 8);
    u2[p] = *(const uint4*)(cell + 16);
  }

  fx4 o0, o1, o2;
#pragma unroll
  for (int p = 0; p < 4; p++) {
    float fR = frv[0][p], fG = frv[1][p], fB = frv[2][p];
    float a0 = trilerp_cell(u0[p], fR, fG, fB);
    float a1 = trilerp_cell(u1[p], fR, fG, fB);
    float a2 = trilerp_cell(u2[p], fR, fG, fB);
    if (p == 0) { o0.x = a0; o1.x = a1; o2.x = a2; }
    if (p == 1) { o0.y = a0; o1.y = a1; o2.y = a2; }
    if (p == 2) { o0.z = a0; o1.z = a1; o2.z = a2; }
    if (p == 3) { o0.w = a0; o1.w = a1; o2.w = a2; }
  }
  __builtin_nontemporal_store(o0, (fx4*)(op + pix));
  __builtin_nontemporal_store(o1, (fx4*)(op + N + pix));
  __builtin_nontemporal_store(o2, (fx4*)(op + 2*N + pix));
}

// ================= launch =================
extern "C" void kernel_launch(void* const* d_in, const int* in_sizes, int n_in,
                              void* d_out, int out_size, void* d_ws, size_t ws_size,
                              hipStream_t stream) {
  const float* imgs = (const float*)d_in[0];
  const float* w1 = (const float*)d_in[1];  const float* b1 = (const float*)d_in[2];
  const float* g1 = (const float*)d_in[3];  const float* be1 = (const float*)d_in[4];
  const float* w2 = (const float*)d_in[5];  const float* b2 = (const float*)d_in[6];
  const float* g2 = (const float*)d_in[7];  const float* be2 = (const float*)d_in[8];
  const float* w3 = (const float*)d_in[9];  const float* b3 = (const float*)d_in[10];
  const float* g3 = (const float*)d_in[11]; const float* be3 = (const float*)d_in[12];
  const float* w4 = (const float*)d_in[13]; const float* b4 = (const float*)d_in[14];
  const float* g4 = (const float*)d_in[15]; const float* be4 = (const float*)d_in[16];
  const float* w5 = (const float*)d_in[17]; const float* b5 = (const float*)d_in[18];
  const float* wgen_w  = (const float*)d_in[19];
  const float* wgen_b  = (const float*)d_in[20];
  const float* basis_w = (const float*)d_in[21];
  const float* ada_w   = (const float*)d_in[22];
  const float* ada_b   = (const float*)d_in[23];
  float* out = (float*)d_out;

  const int B = in_sizes[0] / (3*2048*2048);

  // workspace: region A (x1..x5 stack, later overwritten by ecell) + tail
  char* wsb = (char*)d_ws;
  __half* ecell = (__half*)wsb;                 // B * 2,097,152 bytes
  size_t A_bytes = (size_t)B * 2097152;
  float* x1 = (float*)wsb;                      // B*262144
  float* x2 = x1 + (size_t)B*262144;            // B*131072
  float* x3 = x2 + (size_t)B*131072;            // B*65536
  float* x4 = x3 + (size_t)B*65536;             // B*32768
  float* x5 = x4 + (size_t)B*32768;             // B*8192  (ends < A_bytes)
  float* tail = (float*)(wsb + A_bytes);
  float* gw   = tail;                           // B*4
  float* vert = gw + (size_t)B*4;               // B*99
  uint8_t* hints = (uint8_t*)(vert + (size_t)B*99);  // B*3072 bytes
  // zero-zone: barrier counters (512 B) + channel sum/sumsq buffers
  uintptr_t zz = ((uintptr_t)(hints + (size_t)B*3072) + 511) & ~(uintptr_t)511;
  unsigned* ctr = (unsigned*)zz;                // 8 slots x 16 uints = 512 B
  float* S1 = (float*)(zz + 512);               // B*16
  float* Q1 = S1 + (size_t)B*16;
  float* S2 = Q1 + (size_t)B*16;                // B*32
  float* Q2 = S2 + (size_t)B*32;
  float* S3 = Q2 + (size_t)B*32;                // B*64
  float* Q3 = S3 + (size_t)B*64;
  float* S4 = Q3 + (size_t)B*64;                // B*128
  float* Q4 = S4 + (size_t)B*128;
  float* logits_g = Q4 + (size_t)B*128;         // B*96 (not zeroed; fully written)
  size_t zbytes = 512 + (size_t)B*480*sizeof(float);

  hipMemsetAsync((void*)ctr, 0, zbytes, stream);
  pipeline_kernel<<<960, 256, 0, stream>>>(imgs,
      w1, b1, g1, be1, w2, b2, g2, be2, w3, b3, g3, be3, w4, b4, g4, be4,
      w5, b5, wgen_w, wgen_b, basis_w, ada_w, ada_b,
      x1, x2, x3, x4, x5,
      S1, Q1, S2, Q2, S3, Q3, S4, Q4,
      logits_g, gw, vert, hints, ecell, ctr, B);
  transform_kernel<<<B*4096, 256, 0, stream>>>(imgs, ecell, vert,
                                               (const unsigned int*)hints, out, B);
}

// Round 6
// 548.773 us; speedup vs baseline: 1.7204x; 1.7204x over previous
//
#include <hip/hip_runtime.h>
#include <hip/hip_fp16.h>
#include <cstdint>
#include <cstddef>

#define VCUBE 35937      // 33^3
#define LUT_CH 107811    // 3*33^3

typedef float fx4 __attribute__((ext_vector_type(4)));

// ================= conv1: fused resize(2048->256) + conv3x3s2 + lrelu + S/Q emit =================
// block: (b, oh, ow_tile of 16); threads 256 = 16 co x 16 ow
__global__ __launch_bounds__(256) void conv1_fused(const float* __restrict__ imgs,
    const float* __restrict__ w, const float* __restrict__ bias,
    float* __restrict__ out, float* __restrict__ So, float* __restrict__ Qo) {
  __shared__ float s_in[3*3*34];
  __shared__ float s_w[16*3*9];
  int bid = blockIdx.x;
  int owt = bid & 7; int oh = (bid >> 3) & 127; int b = bid >> 10;
  int t = threadIdx.x;
  int ow0 = owt * 16;
  int iwbase = 2*ow0 - 1;
  int ihbase = 2*oh - 1;
  for (int i = t; i < 3*3*34; i += 256) {
    int x = i % 34; int rest = i / 34; int kh = rest % 3; int ci = rest / 3;
    int ih = ihbase + kh;          // resized-image row
    int iw = iwbase + x;           // resized-image col
    float v = 0.f;
    if (ih >= 0 && ih < 256 && iw >= 0 && iw < 256) {
      const float* p = imgs + (size_t)(b*3+ci) * 2048 * 2048;
      int y0 = ih*8 + 3, x0 = iw*8 + 3;     // scale-8 bilinear: frac exactly 0.5
      const float* r0 = p + (size_t)y0*2048 + x0;
      const float* r1 = r0 + 2048;
      float a = r0[0], bb = r0[1], c = r1[0], d = r1[1];
      float top = a + 0.5f*(bb - a);
      float bot = c + 0.5f*(d - c);
      v = top + 0.5f*(bot - top);
    }
    s_in[i] = v;
  }
  for (int i = t; i < 16*3*9; i += 256) s_w[i] = w[i];
  __syncthreads();
  int owl = t & 15; int co = t >> 4;
  float acc = bias[co];
  const float* wp = s_w + co*27;
#pragma unroll
  for (int ci = 0; ci < 3; ci++) {
#pragma unroll
    for (int kh = 0; kh < 3; kh++) {
      const float* rp = s_in + (ci*3 + kh)*34 + 2*owl;
      acc = fmaf(rp[0], wp[ci*9 + kh*3 + 0], acc);
      acc = fmaf(rp[1], wp[ci*9 + kh*3 + 1], acc);
      acc = fmaf(rp[2], wp[ci*9 + kh*3 + 2], acc);
    }
  }
  acc = acc >= 0.f ? acc : 0.2f*acc;
  out[(((size_t)b*16 + co)*128 + oh)*128 + ow0 + owl] = acc;
  // per-channel partial sums over the 16 ow lanes of this co
  float s = acc, s2 = acc*acc;
#pragma unroll
  for (int off = 1; off < 16; off <<= 1) {
    s  += __shfl_xor(s,  off);
    s2 += __shfl_xor(s2, off);
  }
  if (owl == 0) {
    atomicAdd(&So[b*16 + co], s);
    atomicAdd(&Qo[b*16 + co], s2);
  }
}

// ================= conv3x3 s2 pad1 + lrelu; on-load inorm of input; optional S/Q emit =================
// block: (b, oh, co_group); threads 256 = COPB x OS
template<int CI, int CO, int IS, int COPB, bool WLDS, bool EMIT>
__global__ __launch_bounds__(256) void conv_fused(const float* __restrict__ in,
    const float* __restrict__ w, const float* __restrict__ bias,
    const float* __restrict__ Si, const float* __restrict__ Qi,
    const float* __restrict__ gn, const float* __restrict__ ben,
    float* __restrict__ out, float* __restrict__ So, float* __restrict__ Qo) {
  constexpr int OS = IS/2;
  constexpr int PW = IS + 2;
  constexpr int NG = CO/COPB;
  constexpr int E  = CI*3*PW;
  constexpr float inv_n = 1.0f / (float)(IS*IS);
  static_assert(COPB*OS == 256, "block mismatch");
  __shared__ float s_in[E];
  __shared__ float s_w[WLDS ? COPB*CI*9 : 1];
  __shared__ float snorm[2*CI];
  int bid = blockIdx.x;
  int grp = bid % NG; int rest = bid / NG; int oh = rest % OS; int b = rest / OS;
  int t = threadIdx.x;
  // per-channel scale/shift of the producer's instance norm
  for (int i = t; i < CI; i += 256) {
    float mean = Si[b*CI + i] * inv_n;
    float var  = Qi[b*CI + i] * inv_n - mean*mean;
    float sc   = gn[i] / sqrtf(var + 1e-5f);
    snorm[i]      = sc;
    snorm[CI + i] = ben[i] - mean*sc;
  }
  __syncthreads();
  int ihb = 2*oh - 1;
  for (int i = t; i < E; i += 256) {
    int x = i % PW; int r2 = i / PW; int kh = r2 % 3; int ci = r2 / 3;
    int ih = ihb + kh; int iw = x - 1;
    float v = 0.f;
    if (ih >= 0 && ih < IS && iw >= 0 && iw < IS) {
      v = in[((size_t)(b*CI + ci)*IS + ih)*IS + iw];
      v = fmaf(v, snorm[ci], snorm[CI + ci]);
    }
    s_in[i] = v;
  }
  if (WLDS) {
    const float* wg = w + (size_t)grp*COPB*CI*9;
    for (int i = t; i < COPB*CI*9; i += 256) s_w[i] = wg[i];
  }
  __syncthreads();
  int ow = t % OS; int col = t / OS;
  int co = grp*COPB + col;
  float acc = bias[co];
  const float* wp = WLDS ? (s_w + col*CI*9) : (w + (size_t)co*CI*9);
  for (int ci = 0; ci < CI; ci++) {
    const float* rowp = s_in + ci*3*PW;
    const float* wc = wp + ci*9;
#pragma unroll
    for (int kh = 0; kh < 3; kh++) {
      const float* rp = rowp + kh*PW + 2*ow;
      acc = fmaf(rp[0], wc[kh*3 + 0], acc);
      acc = fmaf(rp[1], wc[kh*3 + 1], acc);
      acc = fmaf(rp[2], wc[kh*3 + 2], acc);
    }
  }
  acc = acc >= 0.f ? acc : 0.2f*acc;
  out[(((size_t)b*CO + co)*OS + oh)*OS + ow] = acc;
  if (EMIT) {
    float s = acc, s2 = acc*acc;
#pragma unroll
    for (int off = 1; off < OS; off <<= 1) {
      s  += __shfl_xor(s,  off);
      s2 += __shfl_xor(s2, off);
    }
    if ((t & (OS-1)) == 0) {
      atomicAdd(&So[b*CO + co], s);
      atomicAdd(&Qo[b*CO + co], s2);
    }
  }
}

// ================= head: pool + gemvs + softmax/cumsum + hint tables =================
__global__ __launch_bounds__(128) void head_kernel(const float* __restrict__ x5,
    const float* __restrict__ wgen_w, const float* __restrict__ wgen_b,
    const float* __restrict__ ada_w, const float* __restrict__ ada_b,
    float* __restrict__ gweights, float* __restrict__ vertices,
    uint8_t* __restrict__ hints) {
  int b = blockIdx.x; int t = threadIdx.x;
  __shared__ float xv[512];
  __shared__ float logits[96];
  __shared__ float svp[99];
  // 4x4 avg pool (128,8,8) -> 512
  for (int o = t; o < 512; o += 128) {
    int c = o >> 2; int h2 = (o >> 1) & 1; int w2 = o & 1;
    const float* p = x5 + ((size_t)(b*128 + c))*64 + h2*32 + w2*4;
    float s = 0.f;
#pragma unroll
    for (int h = 0; h < 4; h++)
#pragma unroll
      for (int ww = 0; ww < 4; ww++) s += p[h*8 + ww];
    xv[o] = s * (1.f/16.f);
  }
  __syncthreads();
  if (t < 96) {
    float s = ada_b[t];
    for (int k = 0; k < 512; k++) s = fmaf(xv[k], ada_w[k*96 + t], s);
    logits[t] = s;
  } else if (t < 99) {
    int j = t - 96;
    float s = wgen_b[j];
    for (int k = 0; k < 512; k++) s = fmaf(xv[k], wgen_w[k*3 + j], s);
    gweights[b*3 + j] = s;
  }
  __syncthreads();
  if (t < 3) {
    const float* l = logits + t*32;
    float m = l[0];
#pragma unroll
    for (int i = 1; i < 32; i++) m = fmaxf(m, l[i]);
    float e[32]; float sum = 0.f;
#pragma unroll
    for (int i = 0; i < 32; i++) { e[i] = expf(l[i] - m); sum += e[i]; }
    float inv = 1.0f / sum;
    float* vp = vertices + b*99 + t*33;
    svp[t*33] = 0.f; vp[0] = 0.f;
    float cum = 0.f;
#pragma unroll
    for (int i = 0; i < 32; i++) { cum = fmaf(e[i], inv, cum); svp[t*33 + i + 1] = cum; vp[i + 1] = cum; }
  }
  __syncthreads();
  // 1024-bin hint per channel: searchsorted_right(v, bin/1024)-1 clipped to [0,31]
  for (int e = t; e < 3072; e += 128) {
    int c = e >> 10; int bin = e & 1023;
    float q0 = (float)bin * (1.f/1024.f);
    const float* v = svp + c*33;
    int lo = 0, hi = 33;
    while (lo < hi) { int mid = (lo + hi) >> 1; if (v[mid] <= q0) lo = mid + 1; else hi = mid; }
    int idx = lo - 1; if (idx > 31) idx = 31;
    hints[b*3072 + e] = (uint8_t)idx;
  }
}

// ================= packed fp16 cell table: (bl,g,r) in 32^3, 24 vals + pad = 64B =================
__global__ __launch_bounds__(256) void ecell_build(const float* __restrict__ basis_w,
    const float* __restrict__ gw, __half* __restrict__ ecell, int B) {
  int tid = blockIdx.x*256 + threadIdx.x;
  int total = B * 32768 * 3;
  if (tid >= total) return;
  int cc = tid % 3;
  int cell = tid / 3;
  int r = cell & 31; int g = (cell >> 5) & 31; int bl = (cell >> 10) & 31; int b = cell >> 15;
  float w0 = gw[b*3 + 0], w1 = gw[b*3 + 1], w2 = gw[b*3 + 2];
  union { __half h[8]; uint4 u; } pk;
#pragma unroll
  for (int dbl = 0; dbl < 2; dbl++)
#pragma unroll
    for (int dg = 0; dg < 2; dg++)
#pragma unroll
      for (int dr = 0; dr < 2; dr++) {
        int flat = cc*VCUBE + ((bl + dbl)*33 + (g + dg))*33 + (r + dr);
        float val = w0*basis_w[flat] + w1*basis_w[LUT_CH + flat] + w2*basis_w[2*LUT_CH + flat];
        pk.h[dbl*4 + dg*2 + dr] = __float2half(val);
      }
  *(uint4*)((uint16_t*)ecell + (size_t)cell*32 + cc*8) = pk.u;
}

// ================= transform (R1-proven: 4 px/thread, batched gathers) =================
__device__ __forceinline__ float trilerp_cell(uint4 u, float fR, float fG, float fB) {
  const __half* h = (const __half*)&u;
  float f0 = __half2float(h[0]), f1 = __half2float(h[1]);
  float f2 = __half2float(h[2]), f3 = __half2float(h[3]);
  float f4 = __half2float(h[4]), f5 = __half2float(h[5]);
  float f6 = __half2float(h[6]), f7 = __half2float(h[7]);
  float l00 = fmaf(fR, f1 - f0, f0);
  float l01 = fmaf(fR, f3 - f2, f2);
  float L0  = fmaf(fG, l01 - l00, l00);
  float l10 = fmaf(fR, f5 - f4, f4);
  float l11 = fmaf(fR, f7 - f6, f6);
  float L1  = fmaf(fG, l11 - l10, l10);
  return fmaf(fB, L1 - L0, L0);
}

__global__ __launch_bounds__(256, 4) void transform_kernel(const float* __restrict__ imgs,
    const __half* __restrict__ ecell, const float* __restrict__ vert,
    const unsigned int* __restrict__ hintw,
    float* __restrict__ out, int B) {
  const size_t N = 2048u*2048u;
  __shared__ float sv[112];              // 3 x 36, indices 33..35 padded with 2.0
  __shared__ unsigned int shint_w[768];
  int b = blockIdx.x % B;                // XCD parity split for B=2
  int pblk = blockIdx.x / B;
  int t = threadIdx.x;
  if (t < 108) {
    int c = t / 36, i = t - c*36;
    sv[t] = (i < 33) ? vert[b*99 + c*33 + i] : 2.0f;
  }
  for (int i = t; i < 768; i += 256) shint_w[i] = hintw[b*768 + i];
  __syncthreads();
  const uint8_t* shint = (const uint8_t*)shint_w;
  size_t pix = ((size_t)pblk*256 + t) * 4;
  const float* ip = imgs + (size_t)b*3*N;
  float* op = out + (size_t)b*3*N;
  const __half* ec = ecell + (size_t)b*1048576;

  // streaming (read-once / write-once) -> non-temporal: keep ecell resident in L2
  fx4 r  = __builtin_nontemporal_load((const fx4*)(ip + pix));
  fx4 g  = __builtin_nontemporal_load((const fx4*)(ip + N + pix));
  fx4 bb = __builtin_nontemporal_load((const fx4*)(ip + 2*N + pix));

  float qv[3][4] = { { r.x, r.y, r.z, r.w },
                     { g.x, g.y, g.z, g.w },
                     { bb.x, bb.y, bb.z, bb.w } };
  int   idxv[3][4];
  float frv[3][4];

  // Phase A: all 12 index+frac computations (parallel 5-load window + count).
#pragma unroll
  for (int c = 0; c < 3; c++) {
#pragma unroll
    for (int p = 0; p < 4; p++) {
      float qc = fminf(fmaxf(qv[c][p], 0.f), 1.f);
      int bin = (int)(qc * 1024.f); bin = bin > 1023 ? 1023 : bin;
      int h = shint[(c << 10) + bin];
      const float* vv = sv + c*36 + h;
      float v0 = vv[0], v1 = vv[1], v2 = vv[2], v3 = vv[3], v4 = vv[4];
      int cnt = (int)(v1 <= qc) + (int)(v2 <= qc) + (int)(v3 <= qc);
      int cmax = 31 - h; cnt = cnt < cmax ? cnt : cmax;
      float lo = v0, hi = v1;
      lo = cnt >= 1 ? v1 : lo;  hi = cnt >= 1 ? v2 : hi;
      lo = cnt >= 2 ? v2 : lo;  hi = cnt >= 2 ? v3 : hi;
      lo = cnt >= 3 ? v3 : lo;  hi = cnt >= 3 ? v4 : hi;
      idxv[c][p] = h + cnt;
      float f = (qc - lo) * __builtin_amdgcn_rcpf(fmaxf(hi - lo, 1e-10f));
      frv[c][p] = fminf(fmaxf(f, 0.f), 1.f);
    }
  }

  // Phase B: issue all 12 cell gathers back-to-back (L2-resident table).
  uint4 u0[4], u1[4], u2[4];
#pragma unroll
  for (int p = 0; p < 4; p++) {
    const __half* cell = ec +
        ((size_t)(((idxv[2][p] << 5) + idxv[1][p]) << 5) + idxv[0][p]) * 32;
    u0[p] = *(const uint4*)(cell);
    u1[p] = *(const uint4*)(cell + 8);
    u2[p] = *(const uint4*)(cell + 16);
  }

  // Phase C: trilerp in issue order, assemble outputs.
  fx4 o0, o1, o2;
#pragma unroll
  for (int p = 0; p < 4; p++) {
    float fR = frv[0][p], fG = frv[1][p], fB = frv[2][p];
    float a0 = trilerp_cell(u0[p], fR, fG, fB);
    float a1 = trilerp_cell(u1[p], fR, fG, fB);
    float a2 = trilerp_cell(u2[p], fR, fG, fB);
    if (p == 0) { o0.x = a0; o1.x = a1; o2.x = a2; }
    if (p == 1) { o0.y = a0; o1.y = a1; o2.y = a2; }
    if (p == 2) { o0.z = a0; o1.z = a1; o2.z = a2; }
    if (p == 3) { o0.w = a0; o1.w = a1; o2.w = a2; }
  }
  __builtin_nontemporal_store(o0, (fx4*)(op + pix));
  __builtin_nontemporal_store(o1, (fx4*)(op + N + pix));
  __builtin_nontemporal_store(o2, (fx4*)(op + 2*N + pix));
}

// ================= launch =================
extern "C" void kernel_launch(void* const* d_in, const int* in_sizes, int n_in,
                              void* d_out, int out_size, void* d_ws, size_t ws_size,
                              hipStream_t stream) {
  const float* imgs = (const float*)d_in[0];
  const float* w1 = (const float*)d_in[1];  const float* b1 = (const float*)d_in[2];
  const float* g1 = (const float*)d_in[3];  const float* be1 = (const float*)d_in[4];
  const float* w2 = (const float*)d_in[5];  const float* b2 = (const float*)d_in[6];
  const float* g2 = (const float*)d_in[7];  const float* be2 = (const float*)d_in[8];
  const float* w3 = (const float*)d_in[9];  const float* b3 = (const float*)d_in[10];
  const float* g3 = (const float*)d_in[11]; const float* be3 = (const float*)d_in[12];
  const float* w4 = (const float*)d_in[13]; const float* b4 = (const float*)d_in[14];
  const float* g4 = (const float*)d_in[15]; const float* be4 = (const float*)d_in[16];
  const float* w5 = (const float*)d_in[17]; const float* b5 = (const float*)d_in[18];
  const float* wgen_w  = (const float*)d_in[19];
  const float* wgen_b  = (const float*)d_in[20];
  const float* basis_w = (const float*)d_in[21];
  const float* ada_w   = (const float*)d_in[22];
  const float* ada_b   = (const float*)d_in[23];
  float* out = (float*)d_out;

  const int B = in_sizes[0] / (3*2048*2048);

  // workspace: region A (x1..x5 stack, later overwritten by ecell) + tail
  char* wsb = (char*)d_ws;
  __half* ecell = (__half*)wsb;                 // B * 2,097,152 bytes
  size_t A_bytes = (size_t)B * 2097152;
  float* x1 = (float*)wsb;                      // B*262144
  float* x2 = x1 + (size_t)B*262144;            // B*131072
  float* x3 = x2 + (size_t)B*131072;            // B*65536
  float* x4 = x3 + (size_t)B*65536;             // B*32768
  float* x5 = x4 + (size_t)B*32768;             // B*8192  (ends < A_bytes)
  float* tail = (float*)(wsb + A_bytes);
  float* gw   = tail;                           // B*4
  float* vert = gw + (size_t)B*4;               // B*99
  uint8_t* hints = (uint8_t*)(vert + (size_t)B*99);  // B*3072 bytes
  // zero-zone: channel sum/sumsq buffers (memset before chain)
  uintptr_t zz = ((uintptr_t)(hints + (size_t)B*3072) + 511) & ~(uintptr_t)511;
  float* S1 = (float*)zz;                       // B*16
  float* Q1 = S1 + (size_t)B*16;
  float* S2 = Q1 + (size_t)B*16;                // B*32
  float* Q2 = S2 + (size_t)B*32;
  float* S3 = Q2 + (size_t)B*32;                // B*64
  float* Q3 = S3 + (size_t)B*64;
  float* S4 = Q3 + (size_t)B*64;                // B*128
  float* Q4 = S4 + (size_t)B*128;
  size_t zbytes = (size_t)B*480*sizeof(float);

  hipMemsetAsync((void*)S1, 0, zbytes, stream);
  conv1_fused<<<B*1024, 256, 0, stream>>>(imgs, w1, b1, x1, S1, Q1);
  conv_fused<16, 32, 128, 4, true, true><<<B*512, 256, 0, stream>>>(
      x1, w2, b2, S1, Q1, g1, be1, x2, S2, Q2);
  conv_fused<32, 64, 64, 8, true, true><<<B*256, 256, 0, stream>>>(
      x2, w3, b3, S2, Q2, g2, be2, x3, S3, Q3);
  conv_fused<64, 128, 32, 16, true, true><<<B*128, 256, 0, stream>>>(
      x3, w4, b4, S3, Q3, g3, be3, x4, S4, Q4);
  conv_fused<128, 128, 16, 32, false, false><<<B*32, 256, 0, stream>>>(
      x4, w5, b5, S4, Q4, g4, be4, x5, nullptr, nullptr);
  head_kernel<<<B, 128, 0, stream>>>(x5, wgen_w, wgen_b, ada_w, ada_b, gw, vert, hints);
  ecell_build<<<B*384, 256, 0, stream>>>(basis_w, gw, ecell, B);
  transform_kernel<<<B*4096, 256, 0, stream>>>(imgs, ecell, vert,
                                               (const unsigned int*)hints, out, B);
}

// Round 7
// 434.435 us; speedup vs baseline: 2.1732x; 1.2632x over previous
//
#include <hip/hip_runtime.h>
#include <hip/hip_fp16.h>
#include <cstdint>
#include <cstddef>

#define VCUBE 35937      // 33^3
#define LUT_CH 107811    // 3*33^3

typedef float fx4 __attribute__((ext_vector_type(4)));

// ================= conv1: fused resize(2048->256) + conv3x3s2 + lrelu =================
// one block per (b, oh): 256 threads stage 3ch x 3rows x 258cols (10 reg-staged
// iterations -> ~40 loads in flight per lane), then 16co x 8 ow-tiles of 16.
__global__ __launch_bounds__(256) void conv1_fused(const float* __restrict__ imgs,
    const float* __restrict__ w, const float* __restrict__ bias,
    float* __restrict__ out) {
  __shared__ float s_in[2322];   // 9 rows (3ch x 3kh) x 258 cols
  __shared__ float s_w[432];
  int bid = blockIdx.x;
  int oh = bid & 127; int b = bid >> 7;
  int t = threadIdx.x;
  int ihb = 2*oh - 1;
  // phase 1: issue ALL bilinear source loads into registers (deep MLP)
  float A[10], Bv[10], C[10], D[10];
#pragma unroll
  for (int k = 0; k < 10; k++) {
    int idx = t + k*256;
    A[k] = 0.f; Bv[k] = 0.f; C[k] = 0.f; D[k] = 0.f;
    if (idx < 2322) {
      int x = idx % 258; int rest = idx / 258;   // rest in [0,9)
      int kh = rest % 3; int ci = rest / 3;
      int ih = ihb + kh; int iw = x - 1;
      if (ih >= 0 && ih < 256 && iw >= 0 && iw < 256) {
        const float* r0 = imgs + (size_t)(b*3+ci)*4194304
                        + (size_t)(ih*8 + 3)*2048 + (iw*8 + 3);
        A[k] = r0[0]; Bv[k] = r0[1]; C[k] = r0[2048]; D[k] = r0[2049];
      }
    }
  }
  // phase 2: bilinear combine (frac exactly 0.5) + LDS write
#pragma unroll
  for (int k = 0; k < 10; k++) {
    int idx = t + k*256;
    if (idx < 2322) {
      float top = A[k] + 0.5f*(Bv[k] - A[k]);
      float bot = C[k] + 0.5f*(D[k] - C[k]);
      s_in[idx] = top + 0.5f*(bot - top);
    }
  }
  for (int i = t; i < 432; i += 256) s_w[i] = w[i];
  __syncthreads();
  int owl = t & 15; int co = t >> 4;
  const float* wp = s_w + co*27;
  float bco = bias[co];
#pragma unroll
  for (int tl = 0; tl < 8; tl++) {
    int ow = tl*16 + owl;
    float acc = bco;
#pragma unroll
    for (int ci = 0; ci < 3; ci++) {
#pragma unroll
      for (int kh = 0; kh < 3; kh++) {
        const float* rp = s_in + (ci*3 + kh)*258 + 2*ow;
        const float* wc = wp + ci*9 + kh*3;
        acc = fmaf(rp[0], wc[0], acc);
        acc = fmaf(rp[1], wc[1], acc);
        acc = fmaf(rp[2], wc[2], acc);
      }
    }
    acc = acc >= 0.f ? acc : 0.2f*acc;
    out[(((size_t)b*16 + co)*128 + oh)*128 + ow] = acc;
  }
}

// ================= per-plane stats: S = sum, Q = sumsq (one block per (b,c)) =================
__global__ __launch_bounds__(256) void stats_kernel(const float* __restrict__ x,
    float* __restrict__ S, float* __restrict__ Q, int HW) {
  int plane = blockIdx.x;
  const float* p = x + (size_t)plane * HW;
  int t = threadIdx.x;
  float s = 0.f, s2 = 0.f;
  int n4 = HW >> 2;
  for (int i = t; i < n4; i += 256) {
    fx4 v = *(const fx4*)(p + i*4);
    s += v.x + v.y + v.z + v.w;
    s2 = fmaf(v.x, v.x, s2); s2 = fmaf(v.y, v.y, s2);
    s2 = fmaf(v.z, v.z, s2); s2 = fmaf(v.w, v.w, s2);
  }
  __shared__ float ss[256], sq[256];
  ss[t] = s; sq[t] = s2;
  __syncthreads();
  for (int off = 128; off > 0; off >>= 1) {
    if (t < off) { ss[t] += ss[t + off]; sq[t] += sq[t + off]; }
    __syncthreads();
  }
  if (t == 0) { S[plane] = ss[0]; Q[plane] = sq[0]; }
}

// ================= conv3x3 s2 pad1 + lrelu; instance-norm of input applied on load =================
// block: (b, oh, co_group); threads 256 = COPB x OS
template<int CI, int CO, int IS, int COPB, bool WLDS>
__global__ __launch_bounds__(256) void conv_fused(const float* __restrict__ in,
    const float* __restrict__ w, const float* __restrict__ bias,
    const float* __restrict__ Si, const float* __restrict__ Qi,
    const float* __restrict__ gn, const float* __restrict__ ben,
    float* __restrict__ out) {
  constexpr int OS = IS/2;
  constexpr int PW = IS + 2;
  constexpr int NG = CO/COPB;
  constexpr int E  = CI*3*PW;
  constexpr float inv_n = 1.0f / (float)(IS*IS);
  static_assert(COPB*OS == 256, "block mismatch");
  __shared__ float s_in[E];
  __shared__ float s_w[WLDS ? COPB*CI*9 : 1];
  __shared__ float snorm[2*CI];
  int bid = blockIdx.x;
  int grp = bid % NG; int rest = bid / NG; int oh = rest % OS; int b = rest / OS;
  int t = threadIdx.x;
  // per-channel scale/shift of the producer's instance norm
  for (int i = t; i < CI; i += 256) {
    float mean = Si[b*CI + i] * inv_n;
    float var  = Qi[b*CI + i] * inv_n - mean*mean;
    float sc   = gn[i] / sqrtf(var + 1e-5f);
    snorm[i]      = sc;
    snorm[CI + i] = ben[i] - mean*sc;
  }
  __syncthreads();
  int ihb = 2*oh - 1;
  for (int i = t; i < E; i += 256) {
    int x = i % PW; int r2 = i / PW; int kh = r2 % 3; int ci = r2 / 3;
    int ih = ihb + kh; int iw = x - 1;
    float v = 0.f;
    if (ih >= 0 && ih < IS && iw >= 0 && iw < IS) {
      v = in[((size_t)(b*CI + ci)*IS + ih)*IS + iw];
      v = fmaf(v, snorm[ci], snorm[CI + ci]);
    }
    s_in[i] = v;
  }
  if (WLDS) {
    const float* wg = w + (size_t)grp*COPB*CI*9;
    for (int i = t; i < COPB*CI*9; i += 256) s_w[i] = wg[i];
  }
  __syncthreads();
  int ow = t % OS; int col = t / OS;
  int co = grp*COPB + col;
  float acc = bias[co];
  const float* wp = WLDS ? (s_w + col*CI*9) : (w + (size_t)co*CI*9);
  for (int ci = 0; ci < CI; ci++) {
    const float* rowp = s_in + ci*3*PW;
    const float* wc = wp + ci*9;
#pragma unroll
    for (int kh = 0; kh < 3; kh++) {
      const float* rp = rowp + kh*PW + 2*ow;
      acc = fmaf(rp[0], wc[kh*3 + 0], acc);
      acc = fmaf(rp[1], wc[kh*3 + 1], acc);
      acc = fmaf(rp[2], wc[kh*3 + 2], acc);
    }
  }
  acc = acc >= 0.f ? acc : 0.2f*acc;
  out[(((size_t)b*CO + co)*OS + oh)*OS + ow] = acc;
}

// ================= head: pool + gemvs + softmax/cumsum + hint tables =================
__global__ __launch_bounds__(128) void head_kernel(const float* __restrict__ x5,
    const float* __restrict__ wgen_w, const float* __restrict__ wgen_b,
    const float* __restrict__ ada_w, const float* __restrict__ ada_b,
    float* __restrict__ gweights, float* __restrict__ vertices,
    uint8_t* __restrict__ hints) {
  int b = blockIdx.x; int t = threadIdx.x;
  __shared__ float xv[512];
  __shared__ float logits[96];
  __shared__ float svp[99];
  // 4x4 avg pool (128,8,8) -> 512
  for (int o = t; o < 512; o += 128) {
    int c = o >> 2; int h2 = (o >> 1) & 1; int w2 = o & 1;
    const float* p = x5 + ((size_t)(b*128 + c))*64 + h2*32 + w2*4;
    float s = 0.f;
#pragma unroll
    for (int h = 0; h < 4; h++)
#pragma unroll
      for (int ww = 0; ww < 4; ww++) s += p[h*8 + ww];
    xv[o] = s * (1.f/16.f);
  }
  __syncthreads();
  if (t < 96) {
    float s = ada_b[t];
    for (int k = 0; k < 512; k++) s = fmaf(xv[k], ada_w[k*96 + t], s);
    logits[t] = s;
  } else if (t < 99) {
    int j = t - 96;
    float s = wgen_b[j];
    for (int k = 0; k < 512; k++) s = fmaf(xv[k], wgen_w[k*3 + j], s);
    gweights[b*3 + j] = s;
  }
  __syncthreads();
  if (t < 3) {
    const float* l = logits + t*32;
    float m = l[0];
#pragma unroll
    for (int i = 1; i < 32; i++) m = fmaxf(m, l[i]);
    float e[32]; float sum = 0.f;
#pragma unroll
    for (int i = 0; i < 32; i++) { e[i] = expf(l[i] - m); sum += e[i]; }
    float inv = 1.0f / sum;
    float* vp = vertices + b*99 + t*33;
    svp[t*33] = 0.f; vp[0] = 0.f;
    float cum = 0.f;
#pragma unroll
    for (int i = 0; i < 32; i++) { cum = fmaf(e[i], inv, cum); svp[t*33 + i + 1] = cum; vp[i + 1] = cum; }
  }
  __syncthreads();
  // 1024-bin hint per channel: searchsorted_right(v, bin/1024)-1 clipped to [0,31]
  for (int e = t; e < 3072; e += 128) {
    int c = e >> 10; int bin = e & 1023;
    float q0 = (float)bin * (1.f/1024.f);
    const float* v = svp + c*33;
    int lo = 0, hi = 33;
    while (lo < hi) { int mid = (lo + hi) >> 1; if (v[mid] <= q0) lo = mid + 1; else hi = mid; }
    int idx = lo - 1; if (idx > 31) idx = 31;
    hints[b*3072 + e] = (uint8_t)idx;
  }
}

// ================= packed fp16 cell table: (bl,g,r) in 32^3, 24 vals + pad = 64B =================
__global__ __launch_bounds__(256) void ecell_build(const float* __restrict__ basis_w,
    const float* __restrict__ gw, __half* __restrict__ ecell, int B) {
  int tid = blockIdx.x*256 + threadIdx.x;
  int total = B * 32768 * 3;
  if (tid >= total) return;
  int cc = tid % 3;
  int cell = tid / 3;
  int r = cell & 31; int g = (cell >> 5) & 31; int bl = (cell >> 10) & 31; int b = cell >> 15;
  float w0 = gw[b*3 + 0], w1 = gw[b*3 + 1], w2 = gw[b*3 + 2];
  union { __half h[8]; uint4 u; } pk;
#pragma unroll
  for (int dbl = 0; dbl < 2; dbl++)
#pragma unroll
    for (int dg = 0; dg < 2; dg++)
#pragma unroll
      for (int dr = 0; dr < 2; dr++) {
        int flat = cc*VCUBE + ((bl + dbl)*33 + (g + dg))*33 + (r + dr);
        float val = w0*basis_w[flat] + w1*basis_w[LUT_CH + flat] + w2*basis_w[2*LUT_CH + flat];
        pk.h[dbl*4 + dg*2 + dr] = __float2half(val);
      }
  *(uint4*)((uint16_t*)ecell + (size_t)cell*32 + cc*8) = pk.u;
}

// ================= transform (R1-proven: 4 px/thread, batched gathers) =================
__device__ __forceinline__ float trilerp_cell(uint4 u, float fR, float fG, float fB) {
  const __half* h = (const __half*)&u;
  float f0 = __half2float(h[0]), f1 = __half2float(h[1]);
  float f2 = __half2float(h[2]), f3 = __half2float(h[3]);
  float f4 = __half2float(h[4]), f5 = __half2float(h[5]);
  float f6 = __half2float(h[6]), f7 = __half2float(h[7]);
  float l00 = fmaf(fR, f1 - f0, f0);
  float l01 = fmaf(fR, f3 - f2, f2);
  float L0  = fmaf(fG, l01 - l00, l00);
  float l10 = fmaf(fR, f5 - f4, f4);
  float l11 = fmaf(fR, f7 - f6, f6);
  float L1  = fmaf(fG, l11 - l10, l10);
  return fmaf(fB, L1 - L0, L0);
}

__global__ __launch_bounds__(256, 4) void transform_kernel(const float* __restrict__ imgs,
    const __half* __restrict__ ecell, const float* __restrict__ vert,
    const unsigned int* __restrict__ hintw,
    float* __restrict__ out, int B) {
  const size_t N = 2048u*2048u;
  __shared__ float sv[112];              // 3 x 36, indices 33..35 padded with 2.0
  __shared__ unsigned int shint_w[768];
  int b = blockIdx.x % B;                // XCD parity split for B=2
  int pblk = blockIdx.x / B;
  int t = threadIdx.x;
  if (t < 108) {
    int c = t / 36, i = t - c*36;
    sv[t] = (i < 33) ? vert[b*99 + c*33 + i] : 2.0f;
  }
  for (int i = t; i < 768; i += 256) shint_w[i] = hintw[b*768 + i];
  __syncthreads();
  const uint8_t* shint = (const uint8_t*)shint_w;
  size_t pix = ((size_t)pblk*256 + t) * 4;
  const float* ip = imgs + (size_t)b*3*N;
  float* op = out + (size_t)b*3*N;
  const __half* ec = ecell + (size_t)b*1048576;

  // streaming (read-once / write-once) -> non-temporal: keep ecell resident in L2
  fx4 r  = __builtin_nontemporal_load((const fx4*)(ip + pix));
  fx4 g  = __builtin_nontemporal_load((const fx4*)(ip + N + pix));
  fx4 bb = __builtin_nontemporal_load((const fx4*)(ip + 2*N + pix));

  float qv[3][4] = { { r.x, r.y, r.z, r.w },
                     { g.x, g.y, g.z, g.w },
                     { bb.x, bb.y, bb.z, bb.w } };
  int   idxv[3][4];
  float frv[3][4];

  // Phase A: all 12 index+frac computations (parallel 5-load window + count).
#pragma unroll
  for (int c = 0; c < 3; c++) {
#pragma unroll
    for (int p = 0; p < 4; p++) {
      float qc = fminf(fmaxf(qv[c][p], 0.f), 1.f);
      int bin = (int)(qc * 1024.f); bin = bin > 1023 ? 1023 : bin;
      int h = shint[(c << 10) + bin];
      const float* vv = sv + c*36 + h;
      float v0 = vv[0], v1 = vv[1], v2 = vv[2], v3 = vv[3], v4 = vv[4];
      int cnt = (int)(v1 <= qc) + (int)(v2 <= qc) + (int)(v3 <= qc);
      int cmax = 31 - h; cnt = cnt < cmax ? cnt : cmax;
      float lo = v0, hi = v1;
      lo = cnt >= 1 ? v1 : lo;  hi = cnt >= 1 ? v2 : hi;
      lo = cnt >= 2 ? v2 : lo;  hi = cnt >= 2 ? v3 : hi;
      lo = cnt >= 3 ? v3 : lo;  hi = cnt >= 3 ? v4 : hi;
      idxv[c][p] = h + cnt;
      float f = (qc - lo) * __builtin_amdgcn_rcpf(fmaxf(hi - lo, 1e-10f));
      frv[c][p] = fminf(fmaxf(f, 0.f), 1.f);
    }
  }

  // Phase B: issue all 12 cell gathers back-to-back (L2-resident table).
  uint4 u0[4], u1[4], u2[4];
#pragma unroll
  for (int p = 0; p < 4; p++) {
    const __half* cell = ec +
        ((size_t)(((idxv[2][p] << 5) + idxv[1][p]) << 5) + idxv[0][p]) * 32;
    u0[p] = *(const uint4*)(cell);
    u1[p] = *(const uint4*)(cell + 8);
    u2[p] = *(const uint4*)(cell + 16);
  }

  // Phase C: trilerp in issue order, assemble outputs.
  fx4 o0, o1, o2;
#pragma unroll
  for (int p = 0; p < 4; p++) {
    float fR = frv[0][p], fG = frv[1][p], fB = frv[2][p];
    float a0 = trilerp_cell(u0[p], fR, fG, fB);
    float a1 = trilerp_cell(u1[p], fR, fG, fB);
    float a2 = trilerp_cell(u2[p], fR, fG, fB);
    if (p == 0) { o0.x = a0; o1.x = a1; o2.x = a2; }
    if (p == 1) { o0.y = a0; o1.y = a1; o2.y = a2; }
    if (p == 2) { o0.z = a0; o1.z = a1; o2.z = a2; }
    if (p == 3) { o0.w = a0; o1.w = a1; o2.w = a2; }
  }
  __builtin_nontemporal_store(o0, (fx4*)(op + pix));
  __builtin_nontemporal_store(o1, (fx4*)(op + N + pix));
  __builtin_nontemporal_store(o2, (fx4*)(op + 2*N + pix));
}

// ================= launch =================
extern "C" void kernel_launch(void* const* d_in, const int* in_sizes, int n_in,
                              void* d_out, int out_size, void* d_ws, size_t ws_size,
                              hipStream_t stream) {
  const float* imgs = (const float*)d_in[0];
  const float* w1 = (const float*)d_in[1];  const float* b1 = (const float*)d_in[2];
  const float* g1 = (const float*)d_in[3];  const float* be1 = (const float*)d_in[4];
  const float* w2 = (const float*)d_in[5];  const float* b2 = (const float*)d_in[6];
  const float* g2 = (const float*)d_in[7];  const float* be2 = (const float*)d_in[8];
  const float* w3 = (const float*)d_in[9];  const float* b3 = (const float*)d_in[10];
  const float* g3 = (const float*)d_in[11]; const float* be3 = (const float*)d_in[12];
  const float* w4 = (const float*)d_in[13]; const float* b4 = (const float*)d_in[14];
  const float* g4 = (const float*)d_in[15]; const float* be4 = (const float*)d_in[16];
  const float* w5 = (const float*)d_in[17]; const float* b5 = (const float*)d_in[18];
  const float* wgen_w  = (const float*)d_in[19];
  const float* wgen_b  = (const float*)d_in[20];
  const float* basis_w = (const float*)d_in[21];
  const float* ada_w   = (const float*)d_in[22];
  const float* ada_b   = (const float*)d_in[23];
  float* out = (float*)d_out;

  const int B = in_sizes[0] / (3*2048*2048);

  // workspace: region A (x1..x5 stack, later overwritten by ecell) + tail
  char* wsb = (char*)d_ws;
  __half* ecell = (__half*)wsb;                 // B * 2,097,152 bytes
  size_t A_bytes = (size_t)B * 2097152;
  float* x1 = (float*)wsb;                      // B*262144
  float* x2 = x1 + (size_t)B*262144;            // B*131072
  float* x3 = x2 + (size_t)B*131072;            // B*65536
  float* x4 = x3 + (size_t)B*65536;             // B*32768
  float* x5 = x4 + (size_t)B*32768;             // B*8192  (ends < A_bytes)
  float* tail = (float*)(wsb + A_bytes);
  float* gw   = tail;                           // B*4
  float* vert = gw + (size_t)B*4;               // B*99
  uint8_t* hints = (uint8_t*)(vert + (size_t)B*99);  // B*3072 bytes
  uintptr_t zz = ((uintptr_t)(hints + (size_t)B*3072) + 511) & ~(uintptr_t)511;
  float* S1 = (float*)zz;                       // B*16
  float* Q1 = S1 + (size_t)B*16;
  float* S2 = Q1 + (size_t)B*16;                // B*32
  float* Q2 = S2 + (size_t)B*32;
  float* S3 = Q2 + (size_t)B*32;                // B*64
  float* Q3 = S3 + (size_t)B*64;
  float* S4 = Q3 + (size_t)B*64;                // B*128
  float* Q4 = S4 + (size_t)B*128;

  conv1_fused<<<B*128, 256, 0, stream>>>(imgs, w1, b1, x1);
  stats_kernel<<<B*16, 256, 0, stream>>>(x1, S1, Q1, 128*128);
  conv_fused<16, 32, 128, 4, true><<<B*512, 256, 0, stream>>>(
      x1, w2, b2, S1, Q1, g1, be1, x2);
  stats_kernel<<<B*32, 256, 0, stream>>>(x2, S2, Q2, 64*64);
  conv_fused<32, 64, 64, 8, true><<<B*256, 256, 0, stream>>>(
      x2, w3, b3, S2, Q2, g2, be2, x3);
  stats_kernel<<<B*64, 256, 0, stream>>>(x3, S3, Q3, 32*32);
  conv_fused<64, 128, 32, 16, true><<<B*128, 256, 0, stream>>>(
      x3, w4, b4, S3, Q3, g3, be3, x4);
  stats_kernel<<<B*128, 256, 0, stream>>>(x4, S4, Q4, 16*16);
  conv_fused<128, 128, 16, 32, false><<<B*32, 256, 0, stream>>>(
      x4, w5, b5, S4, Q4, g4, be4, x5);
  head_kernel<<<B, 128, 0, stream>>>(x5, wgen_w, wgen_b, ada_w, ada_b, gw, vert, hints);
  ecell_build<<<B*384, 256, 0, stream>>>(basis_w, gw, ecell, B);
  transform_kernel<<<B*4096, 256, 0, stream>>>(imgs, ecell, vert,
                                               (const unsigned int*)hints, out, B);
}